// Round 4
// baseline (8106.218 us; speedup 1.0000x reference)
//
#include <hip/hip_runtime.h>
#include <hip/hip_bf16.h>
#include <math.h>

typedef __hip_bfloat16 bf16;

static __device__ __forceinline__ float bf2f_bits(unsigned short u) {
    return __uint_as_float(((unsigned)u) << 16);
}
static __device__ __forceinline__ float b2f(bf16 v) { return __bfloat162float(v); }

// ---------------- LayerNorm (+ optional window partition), f32 in -> bf16 out --
// one block (64 threads) per LOCAL token row of C=512
__global__ __launch_bounds__(64) void ln_kernel(
    const float* __restrict__ in, const float* __restrict__ g,
    const float* __restrict__ bta, bf16* __restrict__ out, int windowed)
{
    int lr  = blockIdx.x;          // local row
    int tid = threadIdx.x;         // 0..63
    const float* xr = in + (size_t)lr * 512;
    int c0 = tid * 8;
    float4 f0 = *reinterpret_cast<const float4*>(xr + c0);
    float4 f1 = *reinterpret_cast<const float4*>(xr + c0 + 4);
    float v[8] = { f0.x, f0.y, f0.z, f0.w, f1.x, f1.y, f1.z, f1.w };
    float s = 0.f, s2 = 0.f;
#pragma unroll
    for (int k = 0; k < 8; ++k) { s += v[k]; s2 += v[k] * v[k]; }
#pragma unroll
    for (int off = 32; off; off >>= 1) {
        s  += __shfl_xor(s,  off, 64);
        s2 += __shfl_xor(s2, off, 64);
    }
    float mean = s * (1.0f / 512.0f);
    float var  = s2 * (1.0f / 512.0f) - mean * mean;
    float inv  = rsqrtf(var + 1e-5f);
    size_t drow;
    if (windowed) {
        int b_loc = lr >> 12;
        int l  = lr & 4095;
        int gr = l >> 6, gc = l & 63;
        int wy = gr >> 3, iy = gr & 7, wx = gc >> 3, ix = gc & 7;
        drow = (size_t)((b_loc * 64 + wy * 8 + wx) * 64 + iy * 8 + ix);
    } else {
        drow = (size_t)lr;
    }
    bf16* orow = out + drow * 512;
#pragma unroll
    for (int k = 0; k < 8; ++k) {
        int c = c0 + k;
        orow[c] = __float2bfloat16((v[k] - mean) * inv * g[c] + bta[c]);
    }
}

// ---------------- Tiled GEMM: C[M,N] = A[M,K](bf16) @ W[N,K]^T(f32) + epilogue ---
// modes: 0 = +bias -> bf16 dst
//        1 = +bias + residual(res f32, window-reversed LOCAL idx) -> f32 dst
//        2 = +bias, exact GELU -> bf16 dst
//        3 = +bias + residual(res f32, same local idx) -> f32 dst  (FINAL OUTPUT)
#define TM 64
#define TN 64
#define TK 16
__global__ __launch_bounds__(256) void gemm_kernel(
    const bf16* __restrict__ A, const float* __restrict__ W,
    const float* __restrict__ bias, int N, int K, int mode,
    void* __restrict__ dstv, const float* __restrict__ res)
{
    __shared__ float As[TK][TM + 1];
    __shared__ float Ws[TK][TN + 1];
    int tx = threadIdx.x, ty = threadIdx.y;
    int tid = ty * 16 + tx;
    int mBase = blockIdx.y * TM;     // local row base
    int nBase = blockIdx.x * TN;
    float acc[4][4] = {};
    int lm = tid >> 2;          // 0..63
    int lk = (tid & 3) * 4;     // 0,4,8,12
    const bf16*  Arow = A + (size_t)(mBase + lm) * K + lk;
    const float* Wrow = W + (size_t)(nBase + lm) * K + lk;

    for (int kb = 0; kb < K; kb += TK) {
        ushort4 av = *reinterpret_cast<const ushort4*>(Arow + kb);
        float4  wv = *reinterpret_cast<const float4*>(Wrow + kb);
        As[lk + 0][lm] = bf2f_bits(av.x);
        As[lk + 1][lm] = bf2f_bits(av.y);
        As[lk + 2][lm] = bf2f_bits(av.z);
        As[lk + 3][lm] = bf2f_bits(av.w);
        Ws[lk + 0][lm] = wv.x;
        Ws[lk + 1][lm] = wv.y;
        Ws[lk + 2][lm] = wv.z;
        Ws[lk + 3][lm] = wv.w;
        __syncthreads();
#pragma unroll
        for (int kk = 0; kk < TK; ++kk) {
            float a0 = As[kk][ty * 4 + 0];
            float a1 = As[kk][ty * 4 + 1];
            float a2 = As[kk][ty * 4 + 2];
            float a3 = As[kk][ty * 4 + 3];
            float w0 = Ws[kk][tx * 4 + 0];
            float w1 = Ws[kk][tx * 4 + 1];
            float w2 = Ws[kk][tx * 4 + 2];
            float w3 = Ws[kk][tx * 4 + 3];
            acc[0][0] += a0 * w0; acc[0][1] += a0 * w1; acc[0][2] += a0 * w2; acc[0][3] += a0 * w3;
            acc[1][0] += a1 * w0; acc[1][1] += a1 * w1; acc[1][2] += a1 * w2; acc[1][3] += a1 * w3;
            acc[2][0] += a2 * w0; acc[2][1] += a2 * w1; acc[2][2] += a2 * w2; acc[2][3] += a2 * w3;
            acc[3][0] += a3 * w0; acc[3][1] += a3 * w1; acc[3][2] += a3 * w2; acc[3][3] += a3 * w3;
        }
        __syncthreads();
    }

#pragma unroll
    for (int i = 0; i < 4; ++i) {
#pragma unroll
        for (int j = 0; j < 4; ++j) {
            int m = mBase + ty * 4 + i;       // local row
            int n = nBase + tx * 4 + j;
            float v = acc[i][j] + bias[n];
            if (mode == 0) {
                ((bf16*)dstv)[(size_t)m * N + n] = __float2bfloat16(v);
            } else if (mode == 1) {
                int b_loc = m >> 12, w = (m >> 6) & 63, tk = m & 63;
                int wy = w >> 3, wx = w & 7, iy = tk >> 3, ix = tk & 7;
                int l = ((wy << 3) + iy) * 64 + (wx << 3) + ix;
                size_t idx = ((size_t)(b_loc * 4096 + l)) * 512 + n;
                ((float*)dstv)[idx] = v + res[idx];
            } else if (mode == 2) {
                float gl = 0.5f * v * (1.0f + erff(v * 0.70710678118654752f));
                ((bf16*)dstv)[(size_t)m * N + n] = __float2bfloat16(gl);
            } else { // mode 3: final output, fp32
                size_t idx = (size_t)m * N + n;
                ((float*)dstv)[idx] = v + res[idx];
            }
        }
    }
}

// ---------------- Fused windowed attention ----------------
// one block (64 threads) per (local window, head); thread = query token
__global__ __launch_bounds__(64) void attn_kernel(
    const bf16* __restrict__ qkv, const float* __restrict__ Dofs,
    const float* __restrict__ a_p, const float* __restrict__ b_p,
    const float* __restrict__ a_r, const float* __restrict__ b_r,
    bf16* __restrict__ xattn)
{
    __shared__ float Ksh[64][32];
    __shared__ float Vsh[64][32];
    __shared__ float Ssh[64][65];
    __shared__ float Dsh[64];
    __shared__ float aps[15], bps[15], ars[15], brs[15];

    int bid = blockIdx.x;
    int h   = bid & 15;
    int b_  = bid >> 4;        // local window index
    int bl  = b_ >> 6;         // local batch
    int w   = b_ & 63;
    int wy = w >> 3, wx = w & 7;
    int i = threadIdx.x;

    const bf16* kp = qkv + (size_t)(b_ * 64 + i) * 1536 + 512 + h * 32;
    const bf16* vp = kp + 512;
#pragma unroll
    for (int d = 0; d < 32; ++d) {
        Ksh[i][d] = b2f(kp[d]);
        Vsh[i][d] = b2f(vp[d]);
    }
    {
        int jy = i >> 3, jx = i & 7;
        Dsh[i] = Dofs[(size_t)bl * 4096 + (wy * 8 + jy) * 64 + (wx * 8 + jx)];
    }
    if (i < 15) {
        aps[i] = a_p[i * 16 + h]; bps[i] = b_p[i * 16 + h];
        ars[i] = a_r[i * 16 + h]; brs[i] = b_r[i * 16 + h];
    }
    __syncthreads();

    float q[32];
    const bf16* qp = qkv + (size_t)(b_ * 64 + i) * 1536 + h * 32;
#pragma unroll
    for (int d = 0; d < 32; ++d) q[d] = b2f(qp[d]);

    const float scale = 0.17677669529663687f;       // 1/sqrt(32)
    const float c_az  = 0.09817477042468103f;       // 2*pi/64
    const float c_r   = 0.02454369260617026f;       // 2*pi/256
    int iy = i >> 3, ix = i & 7;

    float mx = -1e30f;
    for (int j = 0; j < 64; ++j) {
        float dot = 0.f;
#pragma unroll
        for (int d = 0; d < 32; ++d) dot += q[d] * Ksh[j][d];
        int jy = j >> 3, jx = j & 7;
        int az = ix - jx, rad = iy - jy;
        int ip = az  < 0 ? az  + 15 : az;
        int ir = rad < 0 ? rad + 15 : rad;
        float azf  = az * c_az;
        float aphi = aps[ip] * __cosf(azf) + bps[ip] * __sinf(azf);
        float ang  = rad * Dsh[j] * c_r;
        float arv  = ars[ir] * __cosf(ang) + brs[ir] * __sinf(ang);
        float sc = dot * scale + aphi + arv;
        Ssh[i][j] = sc;
        mx = fmaxf(mx, sc);
    }
    float sum = 0.f;
    for (int j = 0; j < 64; ++j) {
        float e = __expf(Ssh[i][j] - mx);
        Ssh[i][j] = e;
        sum += e;
    }
    float inv = 1.0f / sum;
    float acc[32] = {};
    for (int j = 0; j < 64; ++j) {
        float p = Ssh[i][j];
#pragma unroll
        for (int d = 0; d < 32; ++d) acc[d] += p * Vsh[j][d];
    }
    bf16* op = xattn + (size_t)(b_ * 64 + i) * 512 + h * 32;
#pragma unroll
    for (int d = 0; d < 32; ++d) op[d] = __float2bfloat16(acc[d] * inv);
}

// ---------------- launch ----------------
extern "C" void kernel_launch(void* const* d_in, const int* in_sizes, int n_in,
                              void* d_out, int out_size, void* d_ws, size_t ws_size,
                              hipStream_t stream)
{
    const float* x      = (const float*)d_in[0];
    const float* D      = (const float*)d_in[1];
    const float* n1g    = (const float*)d_in[2];
    const float* n1b    = (const float*)d_in[3];
    const float* qkv_w  = (const float*)d_in[4];
    const float* qkv_b  = (const float*)d_in[5];
    const float* proj_w = (const float*)d_in[6];
    const float* proj_b = (const float*)d_in[7];
    const float* a_p    = (const float*)d_in[8];
    const float* b_p    = (const float*)d_in[9];
    const float* a_r    = (const float*)d_in[10];
    const float* b_r    = (const float*)d_in[11];
    const float* n2g    = (const float*)d_in[12];
    const float* n2b    = (const float*)d_in[13];
    const float* fc1_w  = (const float*)d_in[14];
    const float* fc1_b  = (const float*)d_in[15];
    const float* fc2_w  = (const float*)d_in[16];
    const float* fc2_b  = (const float*)d_in[17];
    float* out = (float*)d_out;    // fp32 output

    // group-local workspace: 7168 B per row; pick largest G (batches/group) that fits
    int G = 16;
    while (G > 1 && (size_t)G * 4096 * 7168 > ws_size) G >>= 1;
    int NG = 16 / G;
    size_t rowsA = (size_t)G * 4096;            // rows per group

    char* ws = (char*)d_ws;
    float* x2   = (float*)ws;                   // rowsA*512 f32 (group-local)
    bf16*  xw   = (bf16*)(ws + rowsA * 2048);   // rowsA*512 bf16 (also xm)
    bf16*  qkvb = xw + rowsA * 512;             // rowsA*1536 bf16
    bf16*  xatt = qkvb + rowsA * 1536;          // rowsA*512 bf16
    bf16*  xm   = xw;
    bf16*  hbuf = qkvb;                         // rowsA*2048 bf16 (spans qkv+xatt)

    dim3 blk256(16, 16);
    int gy = (int)(rowsA / TM);

    for (int g = 0; g < NG; ++g) {
        size_t r0 = (size_t)g * rowsA;          // global row offset
        // 1. LN1 + window partition -> xw
        hipLaunchKernelGGL(ln_kernel, dim3((int)rowsA), dim3(64), 0, stream,
                           x + r0 * 512, n1g, n1b, xw, 1);
        // 2. QKV GEMM -> qkvb   [rowsA x 1536, K=512]
        hipLaunchKernelGGL(gemm_kernel, dim3(1536 / TN, gy), blk256, 0, stream,
                           xw, qkv_w, qkv_b, 1536, 512, 0, (void*)qkvb, (const float*)nullptr);
        // 3. fused windowed attention -> xatt
        hipLaunchKernelGGL(attn_kernel, dim3(G * 1024), dim3(64), 0, stream,
                           qkvb, D + r0, a_p, b_p, a_r, b_r, xatt);
        // 4. proj GEMM + window-reverse + residual(x) -> x2 (f32, local)
        hipLaunchKernelGGL(gemm_kernel, dim3(512 / TN, gy), blk256, 0, stream,
                           xatt, proj_w, proj_b, 512, 512, 1, (void*)x2, x + r0 * 512);
        // 5. LN2 -> xm
        hipLaunchKernelGGL(ln_kernel, dim3((int)rowsA), dim3(64), 0, stream,
                           x2, n2g, n2b, xm, 0);
        // 6. fc1 GEMM + exact GELU -> hbuf  [rowsA x 2048, K=512]
        hipLaunchKernelGGL(gemm_kernel, dim3(2048 / TN, gy), blk256, 0, stream,
                           xm, fc1_w, fc1_b, 2048, 512, 2, (void*)hbuf, (const float*)nullptr);
        // 7. fc2 GEMM + residual(x2) -> out (fp32)  [K=2048]
        hipLaunchKernelGGL(gemm_kernel, dim3(512 / TN, gy), blk256, 0, stream,
                           hbuf, fc2_w, fc2_b, 512, 2048, 3, (void*)(out + r0 * 512), x2);
    }
}

// Round 5
// 1700.495 us; speedup vs baseline: 4.7670x; 4.7670x over previous
//
#include <hip/hip_runtime.h>
#include <hip/hip_bf16.h>
#include <math.h>

typedef __hip_bfloat16 bf16;
using f32x4  = __attribute__((ext_vector_type(4))) float;
using bf16x8 = __attribute__((ext_vector_type(8))) short;

static __device__ __forceinline__ float b2f(bf16 v) { return __bfloat162float(v); }
static __device__ __forceinline__ short f2b_s(float f) {
    bf16 b = __float2bfloat16(f);
    return *reinterpret_cast<short*>(&b);
}

// async 16B/lane global->LDS; lptr must be the wave-uniform chunk base
static __device__ __forceinline__ void gl_lds16(const void* g, void* l) {
    __builtin_amdgcn_global_load_lds(
        (const __attribute__((address_space(1))) unsigned int*)g,
        (__attribute__((address_space(3))) unsigned int*)l, 16, 0, 0);
}

// ---------------- fp32 -> bf16 weight conversion ----------------
__global__ __launch_bounds__(256) void f2b_kernel(const float* __restrict__ in,
                                                  short* __restrict__ out, int n4)
{
    int i = blockIdx.x * 256 + threadIdx.x;
    if (i < n4) {
        float4 f = reinterpret_cast<const float4*>(in)[i];
        short4 s;
        s.x = f2b_s(f.x); s.y = f2b_s(f.y); s.z = f2b_s(f.z); s.w = f2b_s(f.w);
        reinterpret_cast<short4*>(out)[i] = s;
    }
}

// ---------------- LayerNorm (+ optional window partition), f32 in -> bf16 out --
__global__ __launch_bounds__(64) void ln_kernel(
    const float* __restrict__ in, const float* __restrict__ g,
    const float* __restrict__ bta, bf16* __restrict__ out, int windowed)
{
    int lr  = blockIdx.x;
    int tid = threadIdx.x;
    const float* xr = in + (size_t)lr * 512;
    int c0 = tid * 8;
    float4 f0 = *reinterpret_cast<const float4*>(xr + c0);
    float4 f1 = *reinterpret_cast<const float4*>(xr + c0 + 4);
    float v[8] = { f0.x, f0.y, f0.z, f0.w, f1.x, f1.y, f1.z, f1.w };
    float s = 0.f, s2 = 0.f;
#pragma unroll
    for (int k = 0; k < 8; ++k) { s += v[k]; s2 += v[k] * v[k]; }
#pragma unroll
    for (int off = 32; off; off >>= 1) {
        s  += __shfl_xor(s,  off, 64);
        s2 += __shfl_xor(s2, off, 64);
    }
    float mean = s * (1.0f / 512.0f);
    float var  = s2 * (1.0f / 512.0f) - mean * mean;
    float inv  = rsqrtf(var + 1e-5f);
    size_t drow;
    if (windowed) {
        int b_loc = lr >> 12;
        int l  = lr & 4095;
        int gr = l >> 6, gc = l & 63;
        int wy = gr >> 3, iy = gr & 7, wx = gc >> 3, ix = gc & 7;
        drow = (size_t)((b_loc * 64 + wy * 8 + wx) * 64 + iy * 8 + ix);
    } else {
        drow = (size_t)lr;
    }
    bf16* orow = out + drow * 512;
#pragma unroll
    for (int k = 0; k < 8; ++k) {
        int c = c0 + k;
        orow[c] = __float2bfloat16((v[k] - mean) * inv * g[c] + bta[c]);
    }
}

// ---------------- MFMA GEMM: C[M,N] = A[M,K](bf16) @ W[N,K]^T(bf16) ------------
// 128x128 tile, 4 waves (2x2), each wave 4x4 of mfma_f32_16x16x32_bf16, BK=32.
// modes: 0 = +bias -> bf16 dst
//        1 = +bias + residual(res f32, window-reversed LOCAL idx) -> f32 dst
//        2 = +bias, exact GELU -> bf16 dst
//        3 = +bias + residual(res f32, same local idx) -> f32 dst (final output)
__global__ __launch_bounds__(256) void gemm_mfma(
    const bf16* __restrict__ A, const short* __restrict__ W,
    const float* __restrict__ bias, int N, int K, int mode,
    void* __restrict__ dstv, const float* __restrict__ res)
{
    __shared__ short Asl[128 * 32];   // row stride 32 elems (64 B)
    __shared__ short Bsl[128 * 32];

    int tid  = threadIdx.x;
    int wave = tid >> 6, lane = tid & 63;
    int waveM = wave >> 1, waveN = wave & 1;
    int mBase = blockIdx.y * 128;
    int nBase = blockIdx.x * 128;

    f32x4 acc[4][4] = {};

    // staging: wave w covers rows w*32 .. w*32+31 (two 16-row instructions each)
    int rr   = wave * 32 + (lane >> 2);          // rows w*32 .. w*32+15
    int segE = (lane & 3) * 8;                   // 16B segment within 64B row
    const bf16*  Ag = A + (size_t)(mBase + rr) * K + segE;
    const short* Bg = W + (size_t)(nBase + rr) * K + segE;
    short* Al0 = &Asl[wave * 1024];              // 32 rows * 32 elems
    short* Bl0 = &Bsl[wave * 1024];

    int mf = waveM * 64 + (lane & 15);           // fragment row (A)
    int nf = waveN * 64 + (lane & 15);           // fragment row (B)
    int kq = (lane >> 4) * 8;                    // quad k-offset

    for (int kb = 0; kb < K; kb += 32) {
        gl_lds16(Ag + kb,               Al0);
        gl_lds16(Ag + kb + (size_t)16 * K, Al0 + 512);
        gl_lds16(Bg + kb,               Bl0);
        gl_lds16(Bg + kb + (size_t)16 * K, Bl0 + 512);
        __syncthreads();

        bf16x8 af[4], bfv[4];
#pragma unroll
        for (int i = 0; i < 4; ++i)
            af[i] = *reinterpret_cast<const bf16x8*>(&Asl[(mf + i * 16) * 32 + kq]);
#pragma unroll
        for (int j = 0; j < 4; ++j)
            bfv[j] = *reinterpret_cast<const bf16x8*>(&Bsl[(nf + j * 16) * 32 + kq]);
#pragma unroll
        for (int i = 0; i < 4; ++i)
#pragma unroll
            for (int j = 0; j < 4; ++j)
                acc[i][j] = __builtin_amdgcn_mfma_f32_16x16x32_bf16(af[i], bfv[j], acc[i][j], 0, 0, 0);
        __syncthreads();
    }

    // epilogue: C/D layout col=lane&15, row=(lane>>4)*4+reg
    int rq = (lane >> 4) * 4;
#pragma unroll
    for (int j = 0; j < 4; ++j) {
        int n = nBase + waveN * 64 + j * 16 + (lane & 15);
        float bn = bias[n];
#pragma unroll
        for (int i = 0; i < 4; ++i) {
#pragma unroll
            for (int reg = 0; reg < 4; ++reg) {
                int m = mBase + waveM * 64 + i * 16 + rq + reg;
                float v = acc[i][j][reg] + bn;
                if (mode == 0) {
                    ((bf16*)dstv)[(size_t)m * N + n] = __float2bfloat16(v);
                } else if (mode == 1) {
                    int b_loc = m >> 12, w = (m >> 6) & 63, tk = m & 63;
                    int wy = w >> 3, wx = w & 7, iy = tk >> 3, ix = tk & 7;
                    int l = ((wy << 3) + iy) * 64 + (wx << 3) + ix;
                    size_t idx = ((size_t)(b_loc * 4096 + l)) * 512 + n;
                    ((float*)dstv)[idx] = v + res[idx];
                } else if (mode == 2) {
                    float gl = 0.5f * v * (1.0f + erff(v * 0.70710678118654752f));
                    ((bf16*)dstv)[(size_t)m * N + n] = __float2bfloat16(gl);
                } else {
                    size_t idx = (size_t)m * N + n;
                    ((float*)dstv)[idx] = v + res[idx];
                }
            }
        }
    }
}

// ---------------- Fused windowed attention (unchanged, verified) ----------------
__global__ __launch_bounds__(64) void attn_kernel(
    const bf16* __restrict__ qkv, const float* __restrict__ Dofs,
    const float* __restrict__ a_p, const float* __restrict__ b_p,
    const float* __restrict__ a_r, const float* __restrict__ b_r,
    bf16* __restrict__ xattn)
{
    __shared__ float Ksh[64][32];
    __shared__ float Vsh[64][32];
    __shared__ float Ssh[64][65];
    __shared__ float Dsh[64];
    __shared__ float aps[15], bps[15], ars[15], brs[15];

    int bid = blockIdx.x;
    int h   = bid & 15;
    int b_  = bid >> 4;
    int bl  = b_ >> 6;
    int w   = b_ & 63;
    int wy = w >> 3, wx = w & 7;
    int i = threadIdx.x;

    const bf16* kp = qkv + (size_t)(b_ * 64 + i) * 1536 + 512 + h * 32;
    const bf16* vp = kp + 512;
#pragma unroll
    for (int d = 0; d < 32; ++d) {
        Ksh[i][d] = b2f(kp[d]);
        Vsh[i][d] = b2f(vp[d]);
    }
    {
        int jy = i >> 3, jx = i & 7;
        Dsh[i] = Dofs[(size_t)bl * 4096 + (wy * 8 + jy) * 64 + (wx * 8 + jx)];
    }
    if (i < 15) {
        aps[i] = a_p[i * 16 + h]; bps[i] = b_p[i * 16 + h];
        ars[i] = a_r[i * 16 + h]; brs[i] = b_r[i * 16 + h];
    }
    __syncthreads();

    float q[32];
    const bf16* qp = qkv + (size_t)(b_ * 64 + i) * 1536 + h * 32;
#pragma unroll
    for (int d = 0; d < 32; ++d) q[d] = b2f(qp[d]);

    const float scale = 0.17677669529663687f;
    const float c_az  = 0.09817477042468103f;
    const float c_r   = 0.02454369260617026f;
    int iy = i >> 3, ix = i & 7;

    float mx = -1e30f;
    for (int j = 0; j < 64; ++j) {
        float dot = 0.f;
#pragma unroll
        for (int d = 0; d < 32; ++d) dot += q[d] * Ksh[j][d];
        int jy = j >> 3, jx = j & 7;
        int az = ix - jx, rad = iy - jy;
        int ip = az  < 0 ? az  + 15 : az;
        int ir = rad < 0 ? rad + 15 : rad;
        float azf  = az * c_az;
        float aphi = aps[ip] * __cosf(azf) + bps[ip] * __sinf(azf);
        float ang  = rad * Dsh[j] * c_r;
        float arv  = ars[ir] * __cosf(ang) + brs[ir] * __sinf(ang);
        float sc = dot * scale + aphi + arv;
        Ssh[i][j] = sc;
        mx = fmaxf(mx, sc);
    }
    float sum = 0.f;
    for (int j = 0; j < 64; ++j) {
        float e = __expf(Ssh[i][j] - mx);
        Ssh[i][j] = e;
        sum += e;
    }
    float inv = 1.0f / sum;
    float acc[32] = {};
    for (int j = 0; j < 64; ++j) {
        float p = Ssh[i][j];
#pragma unroll
        for (int d = 0; d < 32; ++d) acc[d] += p * Vsh[j][d];
    }
    bf16* op = xattn + (size_t)(b_ * 64 + i) * 512 + h * 32;
#pragma unroll
    for (int d = 0; d < 32; ++d) op[d] = __float2bfloat16(acc[d] * inv);
}

// ---------------- launch ----------------
extern "C" void kernel_launch(void* const* d_in, const int* in_sizes, int n_in,
                              void* d_out, int out_size, void* d_ws, size_t ws_size,
                              hipStream_t stream)
{
    const float* x      = (const float*)d_in[0];
    const float* D      = (const float*)d_in[1];
    const float* n1g    = (const float*)d_in[2];
    const float* n1b    = (const float*)d_in[3];
    const float* qkv_w  = (const float*)d_in[4];
    const float* qkv_b  = (const float*)d_in[5];
    const float* proj_w = (const float*)d_in[6];
    const float* proj_b = (const float*)d_in[7];
    const float* a_p    = (const float*)d_in[8];
    const float* b_p    = (const float*)d_in[9];
    const float* a_r    = (const float*)d_in[10];
    const float* b_r    = (const float*)d_in[11];
    const float* n2g    = (const float*)d_in[12];
    const float* n2b    = (const float*)d_in[13];
    const float* fc1_w  = (const float*)d_in[14];
    const float* fc1_b  = (const float*)d_in[15];
    const float* fc2_w  = (const float*)d_in[16];
    const float* fc2_b  = (const float*)d_in[17];
    float* out = (float*)d_out;

    // bf16 weights at ws start: 3,145,728 elems = 6,291,456 B
    char* ws = (char*)d_ws;
    short* qkv_wb  = (short*)ws;                 // 1536*512
    short* proj_wb = qkv_wb + 786432;            // 512*512
    short* fc1_wb  = proj_wb + 262144;           // 2048*512
    short* fc2_wb  = fc1_wb + 1048576;           // 512*2048
    char* gws = (char*)(fc2_wb + 1048576);

    // group-local region: 7168 B per row
    int G = 16;
    while (G > 1 && 6291456 + (size_t)G * 4096 * 7168 > ws_size) G >>= 1;
    int NG = 16 / G;
    size_t rowsA = (size_t)G * 4096;

    float* x2   = (float*)gws;                   // rowsA*512 f32
    bf16*  xw   = (bf16*)(gws + rowsA * 2048);   // rowsA*512 bf16 (also xm)
    bf16*  qkvb = xw + rowsA * 512;              // rowsA*1536 bf16
    bf16*  xatt = qkvb + rowsA * 1536;           // rowsA*512 bf16
    bf16*  xm   = xw;
    bf16*  hbuf = qkvb;                          // rowsA*2048 (spans qkv+xatt)

    // convert weights (every call; graph-safe)
    hipLaunchKernelGGL(f2b_kernel, dim3(768),  dim3(256), 0, stream, qkv_w,  qkv_wb,  196608);
    hipLaunchKernelGGL(f2b_kernel, dim3(256),  dim3(256), 0, stream, proj_w, proj_wb,  65536);
    hipLaunchKernelGGL(f2b_kernel, dim3(1024), dim3(256), 0, stream, fc1_w,  fc1_wb,  262144);
    hipLaunchKernelGGL(f2b_kernel, dim3(1024), dim3(256), 0, stream, fc2_w,  fc2_wb,  262144);

    int gy = (int)(rowsA / 128);

    for (int g = 0; g < NG; ++g) {
        size_t r0 = (size_t)g * rowsA;
        // 1. LN1 + window partition -> xw
        hipLaunchKernelGGL(ln_kernel, dim3((int)rowsA), dim3(64), 0, stream,
                           x + r0 * 512, n1g, n1b, xw, 1);
        // 2. QKV GEMM -> qkvb   [rowsA x 1536, K=512]
        hipLaunchKernelGGL(gemm_mfma, dim3(1536 / 128, gy), dim3(256), 0, stream,
                           xw, qkv_wb, qkv_b, 1536, 512, 0, (void*)qkvb, (const float*)nullptr);
        // 3. fused windowed attention -> xatt
        hipLaunchKernelGGL(attn_kernel, dim3(G * 1024), dim3(64), 0, stream,
                           qkvb, D + r0, a_p, b_p, a_r, b_r, xatt);
        // 4. proj GEMM + window-reverse + residual(x) -> x2 (f32)
        hipLaunchKernelGGL(gemm_mfma, dim3(512 / 128, gy), dim3(256), 0, stream,
                           xatt, proj_wb, proj_b, 512, 512, 1, (void*)x2, x + r0 * 512);
        // 5. LN2 -> xm
        hipLaunchKernelGGL(ln_kernel, dim3((int)rowsA), dim3(64), 0, stream,
                           x2, n2g, n2b, xm, 0);
        // 6. fc1 GEMM + exact GELU -> hbuf  [rowsA x 2048, K=512]
        hipLaunchKernelGGL(gemm_mfma, dim3(2048 / 128, gy), dim3(256), 0, stream,
                           xm, fc1_wb, fc1_b, 2048, 512, 2, (void*)hbuf, (const float*)nullptr);
        // 7. fc2 GEMM + residual(x2) -> out (fp32)  [K=2048]
        hipLaunchKernelGGL(gemm_mfma, dim3(512 / 128, gy), dim3(256), 0, stream,
                           hbuf, fc2_wb, fc2_b, 512, 2048, 3, (void*)(out + r0 * 512), x2);
    }
}